// Round 4
// baseline (2402.434 us; speedup 1.0000x reference)
//
#include <hip/hip_runtime.h>
#include <stdint.h>

// dims fixed by the reference
#define TT 512
#define BB 1024
#define SS 64
#define HH 128
#define TBR (TT*BB)

typedef __attribute__((ext_vector_type(8))) short short8;    // 8 x bf16
typedef __attribute__((ext_vector_type(4))) float floatx4;   // MFMA acc
typedef unsigned short u16;
typedef unsigned int u32;

__device__ __forceinline__ float bf2f(u16 u){union{u32 i;float f;}v;v.i=((u32)u)<<16;return v.f;}
__device__ __forceinline__ u16 f2bf(float f){union{float f;u32 i;}v;v.f=f;u32 r=v.i+0x7FFFu+((v.i>>16)&1u);return (u16)(r>>16);}

// Deterministic dtype detector (see R3: bf16 weights -> ~32/32 plausible
// exponents on even u16s; fp32 buffer -> ~4/32). Same answer every call.
__device__ __forceinline__ bool buf_is_bf16(const u16* p) {
  int ok = 0;
#pragma unroll
  for (int i = 0; i < 32; ++i) {
    u32 v = p[2*i] & 0x7FFFu;
    u32 e = v >> 7;
    ok += (v == 0u || (e >= 96u && e <= 128u)) ? 1 : 0;
  }
  return ok >= 24;
}

template<bool BF> __device__ __forceinline__ float ld1(const void* p, size_t i){
  if constexpr (BF) return bf2f(((const u16*)p)[i]);
  else              return ((const float*)p)[i];
}
__device__ __forceinline__ short8 pack8(floatx4 a, floatx4 b){
  short8 r;
  r[0]=(short)f2bf(a[0]); r[1]=(short)f2bf(a[1]); r[2]=(short)f2bf(a[2]); r[3]=(short)f2bf(a[3]);
  r[4]=(short)f2bf(b[0]); r[5]=(short)f2bf(b[1]); r[6]=(short)f2bf(b[2]); r[7]=(short)f2bf(b[3]);
  return r;
}
template<bool BF> __device__ __forceinline__ short8 ld8(const void* p, size_t i){
  if constexpr (BF) return *(const short8*)((const u16*)p + i);
  else {
    const float* f = (const float*)p + i;
    return pack8(*(const floatx4*)f, *(const floatx4*)(f + 4));
  }
}
template<bool BF> __device__ __forceinline__ void st1(void* p, size_t i, float v){
  if constexpr (BF) ((u16*)p)[i] = f2bf(v);
  else              ((float*)p)[i] = v;
}

// LDS-only barrier: all cross-wave state in this kernel lives in LDS, so
// lgkmcnt(0)+s_barrier suffices; skipping the vmcnt(0) drain keeps global
// prefetch loads and head stores in flight across step boundaries.
// 0xC07F = vmcnt 63 (no wait), expcnt 7 (no wait), lgkmcnt 0.
__device__ __forceinline__ void barrier_lds() {
  __asm__ __volatile__("" ::: "memory");
  __builtin_amdgcn_s_waitcnt(0xC07F);
  __builtin_amdgcn_s_barrier();
  __asm__ __volatile__("" ::: "memory");
}

// A-fragment-ordered LDS index for v_mfma_f32_16x16x32_bf16:
// lane (m + 16q) holds A[m][ks*32 + q*8 + j]; fragment read = ds_read_b128
// at u16 offset ks*512 + lane*8.
__device__ __forceinline__ int fragidx(int m,int k){
  return ((k>>5)<<9)+((m+(((k>>3)&3)<<4))<<3)+(k&7);
}

__device__ __forceinline__ floatx4 mfma(short8 a, short8 b, floatx4 c){
  return __builtin_amdgcn_mfma_f32_16x16x32_bf16(a,b,c,0,0,0);
}

// Head finisher (unchanged from R3, which passed). C-frag of logits: lane
// (n16+16q) holds logit[row 4q+r][a=n16]; softmax = 16-lane shuffle group.
template<bool BF>
__device__ __forceinline__ void head_out(
    floatx4 a, int tstep, int wv, int n16, int q,
    float bav, float bcv, const int* abuf_slot, void* __restrict__ out, int b0)
{
  if (wv == 1) {
#pragma unroll
    for (int r = 0; r < 4; ++r) {
      float l = a[r] + bav;
      float mx = l;
#pragma unroll
      for (int d = 1; d < 16; d <<= 1) mx = fmaxf(mx, __shfl_xor(mx, d, 16));
      float e = __expf(l - mx);
      float sum = e;
#pragma unroll
      for (int d = 1; d < 16; d <<= 1) sum += __shfl_xor(sum, d, 16);
      float ls = __logf(sum);
      float lp = l - mx - ls;
      float p = e / sum;
      float ent = -p * lp;
#pragma unroll
      for (int d = 1; d < 16; d <<= 1) ent += __shfl_xor(ent, d, 16);
      int act = abuf_slot[4*q + r];
      float lps = __shfl(lp, act, 16);
      if (n16 == 0) {
        size_t o = ((size_t)tstep*BB + b0 + 4*q + r) * 3;
        st1<BF>(out, o,     lps);
        st1<BF>(out, o + 1, ent);
      }
    }
  } else {
#pragma unroll
    for (int r = 0; r < 4; ++r) {
      if (n16 == 0) {
        size_t o = ((size_t)tstep*BB + b0 + 4*q + r) * 3;
        st1<BF>(out, o + 2, a[r] + bcv);
      }
    }
  }
}

// ---------------------------------------------------------------------------
// Fused MLP + GRU + head. 64 blocks x 512 thr, block owns 16 batch rows.
// Per 2-step batch: MLP (2 full syncs, gx -> fp32 regs), then 2 steps of
// {head(t-1), gh MFMA, gates} each ending in an LDS-only barrier.
// h double-buffered in LDS -> 1 barrier per step for the recurrence.
// ---------------------------------------------------------------------------
template<bool BF>
__global__ __launch_bounds__(512, 2) void k_fused(
    const void* __restrict__ x, const void* __restrict__ done_, const int* __restrict__ action,
    const void* __restrict__ gstate,
    const void* __restrict__ W1, const void* __restrict__ b1,
    const void* __restrict__ W2, const void* __restrict__ b2,
    const void* __restrict__ Wih, const void* __restrict__ bih,
    const void* __restrict__ Whh, const void* __restrict__ bhh,
    const void* __restrict__ Wa, const void* __restrict__ ba,
    const void* __restrict__ Wc, const void* __restrict__ bc,
    void* __restrict__ out)
{
  if (buf_is_bf16((const u16*)W1) != BF) return;

  const int tid = threadIdx.x, lane = tid & 63, wv = tid >> 6;   // wv 0..7
  const int n16 = lane & 15, q = lane >> 4;
  const int b0 = blockIdx.x * 16;
  const int jj = 16*wv + n16;           // this wave's gate/gx column

  __shared__ __align__(16) u16 hbuf[2][2048];   // double-buffered h A-frag
  __shared__ __align__(16) u16 h1f[2][2048];    // per-step h1 A-frag
  __shared__ __align__(16) u16 h2f[2][2048];    // per-step h2 A-frag
  __shared__ float hfp[16][128];                // fp32 h state (lane-exclusive)
  __shared__ __align__(16) u16 waWc[2176];      // rows 0..15 Wa, row 16 Wc
  __shared__ u16 dbuf[8][16];                   // done ring (bf16 0/1), slot t&7
  __shared__ int abuf[8][16];                   // action ring, slot t&7

  // ---- persistent weights -> VGPR B-fragments --------------------------
  short8 w1f[2], w2f[4], wif[3][4], whf[3][4];
  float b1v, b2v, bihv[3], bhv[3];
  {
    int row = wv*16 + n16;
#pragma unroll
    for (int ks = 0; ks < 2; ++ks) w1f[ks] = ld8<BF>(W1, (size_t)row*SS + ks*32 + q*8);
    b1v = ld1<BF>(b1, row);
#pragma unroll
    for (int ks = 0; ks < 4; ++ks) w2f[ks] = ld8<BF>(W2, (size_t)row*HH + ks*32 + q*8);
    b2v = ld1<BF>(b2, row);
#pragma unroll
    for (int g = 0; g < 3; ++g) {
      int grow = g*128 + jj;
#pragma unroll
      for (int ks = 0; ks < 4; ++ks) {
        wif[g][ks] = ld8<BF>(Wih, (size_t)grow*HH + ks*32 + q*8);
        whf[g][ks] = ld8<BF>(Whh, (size_t)grow*HH + ks*32 + q*8);
      }
      bihv[g] = ld1<BF>(bih, grow);
      bhv[g]  = ld1<BF>(bhh, grow);
    }
  }
  const float bav = ld1<BF>(ba, n16);
  const float bcv = ld1<BF>(bc, 0);

  // ---- prologue staging -------------------------------------------------
  if (tid < 256) *(short8*)(waWc + tid*8) = ld8<BF>(Wa, (size_t)tid*8);
  if (tid < 16)  *(short8*)(waWc + 2048 + tid*8) = ld8<BF>(Wc, (size_t)tid*8);
  for (int i = tid; i < 2048; i += 512) {
    int m = i >> 7, c = i & 127;
    float v = ld1<BF>(gstate, (size_t)(b0 + m)*HH + c);
    hfp[m][c] = v;
    hbuf[0][fragidx(m, c)] = f2bf(v);
  }
  if (tid < 32) {            // done/action slots 0,1
    int s = tid >> 4, row = tid & 15;
    size_t idx = (size_t)s*BB + b0 + row;
    dbuf[s][row] = f2bf(ld1<BF>(done_, idx));
    abuf[s][row] = action[idx];
  }
  // x A-frags for batch 0 (each wave holds the full fragment)
  short8 xcur[2][2], xnxt[2][2];
#pragma unroll
  for (int s = 0; s < 2; ++s)
#pragma unroll
    for (int ks = 0; ks < 2; ++ks)
      xcur[s][ks] = ld8<BF>(x, ((size_t)s*BB + b0 + n16)*SS + ks*32 + q*8);
#pragma unroll
  for (int s = 0; s < 2; ++s)
#pragma unroll
    for (int ks = 0; ks < 2; ++ks) { short8 z={0,0,0,0,0,0,0,0}; xnxt[s][ks]=z; }
  u16 dpf = 0; float dpff = 0.f; int apf = 0;
  __syncthreads();

  for (int tb = 0; tb < TT/2; ++tb) {
    const int t0 = 2*tb;

    // park d/a prefetched during batch tb-1 (first read is after B1/B2)
    if (tb > 0 && tid < 32) {
      int s = tid >> 4, row = tid & 15;
      dbuf[(t0+s) & 7][row] = BF ? dpf : f2bf(dpff);
      abuf[(t0+s) & 7][row] = apf;
    }

    // ---- MLP for steps t0, t0+1 ----------------------------------------
#pragma unroll
    for (int s = 0; s < 2; ++s) {
      floatx4 a = {0.f,0.f,0.f,0.f};
      a = mfma(xcur[s][0], w1f[0], a);
      a = mfma(xcur[s][1], w1f[1], a);
#pragma unroll
      for (int r = 0; r < 4; ++r) {
        float v = a[r] + b1v; v = v > 0.f ? v : 0.f;
        h1f[s][fragidx(4*q + r, jj)] = f2bf(v);
      }
    }
    __syncthreads();                                  // B1 (full)
#pragma unroll
    for (int s = 0; s < 2; ++s) {
      short8 h1a[4];
#pragma unroll
      for (int ks = 0; ks < 4; ++ks) h1a[ks] = *(const short8*)(&h1f[s][0] + ks*512 + lane*8);
      floatx4 a = {0.f,0.f,0.f,0.f};
#pragma unroll
      for (int ks = 0; ks < 4; ++ks) a = mfma(h1a[ks], w2f[ks], a);
#pragma unroll
      for (int r = 0; r < 4; ++r) {
        float v = a[r] + b2v; v = v > 0.f ? v : 0.f;
        h2f[s][fragidx(4*q + r, jj)] = f2bf(v);
      }
    }
    __syncthreads();                                  // B2 (full)
    floatx4 agx[2][3];                                // gx in fp32 registers
#pragma unroll
    for (int s = 0; s < 2; ++s) {
      short8 h2a[4];
#pragma unroll
      for (int ks = 0; ks < 4; ++ks) h2a[ks] = *(const short8*)(&h2f[s][0] + ks*512 + lane*8);
#pragma unroll
      for (int g = 0; g < 3; ++g) {
        floatx4 a = {0.f,0.f,0.f,0.f};
#pragma unroll
        for (int ks = 0; ks < 4; ++ks) a = mfma(h2a[ks], wif[g][ks], a);
        agx[s][g] = a;
      }
    }

    // issue next batch's global prefetch (~2 steps of latency cover;
    // no full barrier occurs until after these are consumed)
    if (t0 + 2 < TT) {
      if constexpr (BF) {
#pragma unroll
        for (int s = 0; s < 2; ++s)
#pragma unroll
          for (int ks = 0; ks < 2; ++ks)
            xnxt[s][ks] = *(const short8*)((const u16*)x +
                          ((size_t)(t0+2+s)*BB + b0 + n16)*SS + ks*32 + q*8);
      }
      if (tid < 32) {
        int s = tid >> 4, row = tid & 15;
        size_t idx = (size_t)(t0+2+s)*BB + b0 + row;
        if constexpr (BF) dpf = ((const u16*)done_)[idx];
        else              dpff = ((const float*)done_)[idx];
        apf = action[idx];
      }
    }

    // ---- 2 recurrence steps --------------------------------------------
#pragma unroll
    for (int s = 0; s < 2; ++s) {
      const int t = t0 + s, p = t & 1;
      short8 haf[4];
#pragma unroll
      for (int ks = 0; ks < 4; ++ks) haf[ks] = *(const short8*)(&hbuf[p][0] + ks*512 + lane*8);

      // head for t-1 first: stores get the whole step to retire
      if (t > 0 && (wv == 1 || wv == 2)) {
        short8 scf[4];
#pragma unroll
        for (int ks = 0; ks < 4; ++ks) {
          short8 z = {0,0,0,0,0,0,0,0};
          if (wv == 1)          z = *(const short8*)(waWc + n16*128 + ks*32 + q*8);
          else if (n16 == 0)    z = *(const short8*)(waWc + 2048 + ks*32 + q*8);
          scf[ks] = z;
        }
        floatx4 a = {0.f,0.f,0.f,0.f};
#pragma unroll
        for (int ks = 0; ks < 4; ++ks) a = mfma(haf[ks], scf[ks], a);
        head_out<BF>(a, t-1, wv, n16, q, bav, bcv, &abuf[(t-1) & 7][0], out, b0);
      }

      floatx4 agh[3];
#pragma unroll
      for (int g = 0; g < 3; ++g) {
        floatx4 a = {0.f,0.f,0.f,0.f};
#pragma unroll
        for (int ks = 0; ks < 4; ++ks) a = mfma(haf[ks], whf[g][ks], a);
        agh[g] = a;
      }

      // gates: lane owns (rows 4q+r, col jj)
#pragma unroll
      for (int r = 0; r < 4; ++r) {
        int row = 4*q + r;
        float s4 = 1.f - bf2f(dbuf[t & 7][row]);
        float xr = agx[s][0][r] + bihv[0];
        float xz = agx[s][1][r] + bihv[1];
        float xn = agx[s][2][r] + bihv[2];
        float hr = s4*agh[0][r] + bhv[0];   // done-mask: gh linear in h
        float hz = s4*agh[1][r] + bhv[1];
        float hn = s4*agh[2][r] + bhv[2];
        float rg = 1.f / (1.f + __expf(-(xr + hr)));
        float zg = 1.f / (1.f + __expf(-(xz + hz)));
        float ni = xn + rg*hn;
        float ng = 2.f / (1.f + __expf(-2.f*ni)) - 1.f;   // tanh
        float hold = hfp[row][jj] * s4;
        float hnew = (1.f - zg)*ng + zg*hold;
        hfp[row][jj] = hnew;
        hbuf[1 - p][fragidx(row, jj)] = f2bf(hnew);
        if (t == TT - 1)
          st1<BF>(out, (size_t)3*TBR + (size_t)(b0 + row)*HH + jj, hnew);
      }
      barrier_lds();                                  // Bs (LDS-only)
    }

    if constexpr (BF) {
#pragma unroll
      for (int s = 0; s < 2; ++s) { xcur[s][0] = xnxt[s][0]; xcur[s][1] = xnxt[s][1]; }
    } else {
      if (t0 + 2 < TT) {
#pragma unroll
        for (int s = 0; s < 2; ++s)
#pragma unroll
          for (int ks = 0; ks < 2; ++ks)
            xcur[s][ks] = ld8<false>(x, ((size_t)(t0+2+s)*BB + b0 + n16)*SS + ks*32 + q*8);
      }
    }
  }

  // epilogue: head for t = TT-1 (h_511 sits in hbuf[0])
  {
    short8 haf[4];
#pragma unroll
    for (int ks = 0; ks < 4; ++ks) haf[ks] = *(const short8*)(&hbuf[0][0] + ks*512 + lane*8);
    if (wv == 1 || wv == 2) {
      short8 scf[4];
#pragma unroll
      for (int ks = 0; ks < 4; ++ks) {
        short8 z = {0,0,0,0,0,0,0,0};
        if (wv == 1)          z = *(const short8*)(waWc + n16*128 + ks*32 + q*8);
        else if (n16 == 0)    z = *(const short8*)(waWc + 2048 + ks*32 + q*8);
        scf[ks] = z;
      }
      floatx4 a = {0.f,0.f,0.f,0.f};
#pragma unroll
      for (int ks = 0; ks < 4; ++ks) a = mfma(haf[ks], scf[ks], a);
      head_out<BF>(a, TT-1, wv, n16, q, bav, bcv, &abuf[(TT-1) & 7][0], out, b0);
    }
  }
}

// ---------------------------------------------------------------------------
extern "C" void kernel_launch(void* const* d_in, const int* in_sizes, int n_in,
                              void* d_out, int out_size, void* d_ws, size_t ws_size,
                              hipStream_t stream) {
  const void* x    = d_in[0];
  const void* done = d_in[1];
  const int*  act  = (const int*)d_in[2];
  const void* gst  = d_in[3];
  const void* W1   = d_in[4];
  const void* b1   = d_in[5];
  const void* W2   = d_in[6];
  const void* b2   = d_in[7];
  const void* Wih  = d_in[8];
  const void* bih  = d_in[9];
  const void* Whh  = d_in[10];
  const void* bhh  = d_in[11];
  const void* Wa   = d_in[12];
  const void* ba   = d_in[13];
  const void* Wc   = d_in[14];
  const void* bc   = d_in[15];

  hipLaunchKernelGGL((k_fused<true>),  dim3(64), dim3(512), 0, stream,
                     x, done, act, gst, W1, b1, W2, b2, Wih, bih,
                     Whh, bhh, Wa, ba, Wc, bc, d_out);
  hipLaunchKernelGGL((k_fused<false>), dim3(64), dim3(512), 0, stream,
                     x, done, act, gst, W1, b1, W2, b2, Wih, bih,
                     Whh, bhh, Wa, ba, Wc, bc, d_out);
}

// Round 5
// 1388.655 us; speedup vs baseline: 1.7300x; 1.7300x over previous
//
#include <hip/hip_runtime.h>
#include <stdint.h>

// dims fixed by the reference
#define TT 512
#define BB 1024
#define SS 64
#define HH 128
#define TBR (TT*BB)

typedef __attribute__((ext_vector_type(8))) short short8;    // 8 x bf16
typedef __attribute__((ext_vector_type(4))) float floatx4;   // MFMA acc
typedef unsigned short u16;
typedef unsigned int u32;
typedef struct { u32 x, y; } u32x2;

__device__ __forceinline__ float bf2f(u16 u){union{u32 i;float f;}v;v.i=((u32)u)<<16;return v.f;}
__device__ __forceinline__ u16 f2bf(float f){union{float f;u32 i;}v;v.f=f;u32 r=v.i+0x7FFFu+((v.i>>16)&1u);return (u16)(r>>16);}
__device__ __forceinline__ float frcp(float x){ return __builtin_amdgcn_rcpf(x); }

// Deterministic dtype detector (R3-proven): bf16 weight buffer -> ~32/32
// plausible exponents on even u16s; fp32 buffer -> ~4/32.
__device__ __forceinline__ bool buf_is_bf16(const u16* p) {
  int ok = 0;
#pragma unroll
  for (int i = 0; i < 32; ++i) {
    u32 v = p[2*i] & 0x7FFFu;
    u32 e = v >> 7;
    ok += (v == 0u || (e >= 96u && e <= 128u)) ? 1 : 0;
  }
  return ok >= 24;
}

template<bool BF> __device__ __forceinline__ float ld1(const void* p, size_t i){
  if constexpr (BF) return bf2f(((const u16*)p)[i]);
  else              return ((const float*)p)[i];
}
__device__ __forceinline__ short8 pack8(floatx4 a, floatx4 b){
  short8 r;
  r[0]=(short)f2bf(a[0]); r[1]=(short)f2bf(a[1]); r[2]=(short)f2bf(a[2]); r[3]=(short)f2bf(a[3]);
  r[4]=(short)f2bf(b[0]); r[5]=(short)f2bf(b[1]); r[6]=(short)f2bf(b[2]); r[7]=(short)f2bf(b[3]);
  return r;
}
template<bool BF> __device__ __forceinline__ short8 ld8(const void* p, size_t i){
  if constexpr (BF) return *(const short8*)((const u16*)p + i);
  else {
    const float* f = (const float*)p + i;
    return pack8(*(const floatx4*)f, *(const floatx4*)(f + 4));
  }
}
template<bool BF> __device__ __forceinline__ void st1(void* p, size_t i, float v){
  if constexpr (BF) ((u16*)p)[i] = f2bf(v);
  else              ((float*)p)[i] = v;
}

// LDS-only barrier (R4-proven): lgkmcnt(0)+s_barrier, no vmcnt drain.
__device__ __forceinline__ void barrier_lds() {
  __asm__ __volatile__("" ::: "memory");
  __builtin_amdgcn_s_waitcnt(0xC07F);
  __builtin_amdgcn_s_barrier();
  __asm__ __volatile__("" ::: "memory");
}

// A-fragment-ordered LDS index for v_mfma_f32_16x16x32_bf16 (R3/R4-proven).
__device__ __forceinline__ int fragidx(int m,int k){
  return ((k>>5)<<9)+((m+(((k>>3)&3)<<4))<<3)+(k&7);
}
__device__ __forceinline__ floatx4 mfma(short8 a, short8 b, floatx4 c){
  return __builtin_amdgcn_mfma_f32_16x16x32_bf16(a,b,c,0,0,0);
}

// ---------------------------------------------------------------------------
// K2: fused MLP + GRU scan. 64 blocks x 512 thr, block owns 16 batch rows.
// Head softmax REMOVED: raw logits/value stored fp32 to workspace (K3 does
// softmax). h fp32 state in registers. rcp-based sigmoids.
// ---------------------------------------------------------------------------
template<bool BF>
__global__ __launch_bounds__(512, 2) void k_scan(
    const void* __restrict__ x, const void* __restrict__ done_,
    const void* __restrict__ gstate,
    const void* __restrict__ W1, const void* __restrict__ b1,
    const void* __restrict__ W2, const void* __restrict__ b2,
    const void* __restrict__ Wih, const void* __restrict__ bih,
    const void* __restrict__ Whh, const void* __restrict__ bhh,
    const void* __restrict__ Wa, const void* __restrict__ ba,
    const void* __restrict__ Wc, const void* __restrict__ bc,
    float* __restrict__ lgws, float* __restrict__ vws,
    void* __restrict__ out)
{
  if (buf_is_bf16((const u16*)W1) != BF) return;

  const int tid = threadIdx.x, lane = tid & 63, wv = tid >> 6;   // wv 0..7
  const int n16 = lane & 15, q = lane >> 4;
  const int b0 = blockIdx.x * 16;
  const int jj = 16*wv + n16;           // this wave's gate/gx column

  __shared__ __align__(16) u16 hbuf[2][2048];   // double-buffered h A-frag
  __shared__ __align__(16) u16 h1f[2][2048];    // per-step h1 A-frag
  __shared__ __align__(16) u16 h2f[2][2048];    // per-step h2 A-frag

  // ---- weights -> VGPR/AGPR B-fragments --------------------------------
  short8 w1f[2], w2f[4], wif[3][4], whf[3][4], scf[4];
  float b1v, b2v, bihv2, bhv2, bb0, bb1;        // folded r/z biases
  {
    int row = wv*16 + n16;
#pragma unroll
    for (int ks = 0; ks < 2; ++ks) w1f[ks] = ld8<BF>(W1, (size_t)row*SS + ks*32 + q*8);
    b1v = ld1<BF>(b1, row);
#pragma unroll
    for (int ks = 0; ks < 4; ++ks) w2f[ks] = ld8<BF>(W2, (size_t)row*HH + ks*32 + q*8);
    b2v = ld1<BF>(b2, row);
    float bi0, bi1, bh0, bh1;
#pragma unroll
    for (int g = 0; g < 3; ++g) {
      int grow = g*128 + jj;
#pragma unroll
      for (int ks = 0; ks < 4; ++ks) {
        wif[g][ks] = ld8<BF>(Wih, (size_t)grow*HH + ks*32 + q*8);
        whf[g][ks] = ld8<BF>(Whh, (size_t)grow*HH + ks*32 + q*8);
      }
      float bi = ld1<BF>(bih, grow), bh = ld1<BF>(bhh, grow);
      if (g == 0) { bi0 = bi; bh0 = bh; }
      else if (g == 1) { bi1 = bi; bh1 = bh; }
      else { bihv2 = bi; bhv2 = bh; }
    }
    bb0 = bi0 + bh0;   // sigmoid args: gx + (s4*gh + bh) + bi = gx + fma(s4,gh,bb)
    bb1 = bi1 + bh1;
  }
  if (wv == 1) {
#pragma unroll
    for (int ks = 0; ks < 4; ++ks) scf[ks] = ld8<BF>(Wa, (size_t)n16*HH + ks*32 + q*8);
  } else if (wv == 2) {
#pragma unroll
    for (int ks = 0; ks < 4; ++ks) {
      short8 z = {0,0,0,0,0,0,0,0};
      if (n16 == 0) z = ld8<BF>(Wc, (size_t)ks*32 + q*8);
      scf[ks] = z;
    }
  } else {
#pragma unroll
    for (int ks = 0; ks < 4; ++ks) { short8 z = {0,0,0,0,0,0,0,0}; scf[ks] = z; }
  }
  const float bav = ld1<BF>(ba, n16);
  const float bcv = ld1<BF>(bc, 0);

  // ---- h0 state: fp32 in registers + bf16 frag in LDS ------------------
  float hreg[4];
#pragma unroll
  for (int r = 0; r < 4; ++r) {
    hreg[r] = ld1<BF>(gstate, (size_t)(b0 + 4*q + r)*HH + jj);
    hbuf[0][fragidx(4*q + r, jj)] = f2bf(hreg[r]);
  }
  // x + done for batch 0
  short8 xc[2][2], xn[2][2];
#pragma unroll
  for (int s = 0; s < 2; ++s)
#pragma unroll
    for (int ks = 0; ks < 2; ++ks)
      xc[s][ks] = ld8<BF>(x, ((size_t)s*BB + b0 + n16)*SS + ks*32 + q*8);
  float s4cur[2][4];
#pragma unroll
  for (int s = 0; s < 2; ++s)
#pragma unroll
    for (int r = 0; r < 4; ++r)
      s4cur[s][r] = 1.f - ld1<BF>(done_, (size_t)s*BB + b0 + 4*q + r);
  u32x2 draw[2];  floatx4 fdraw[2];     // raw next-batch done (dtype-specific)
#pragma unroll
  for (int s = 0; s < 2; ++s) { draw[s].x = draw[s].y = 0; fdraw[s] = floatx4{0,0,0,0}; }
#pragma unroll
  for (int s = 0; s < 2; ++s)
#pragma unroll
    for (int ks = 0; ks < 2; ++ks) { short8 z={0,0,0,0,0,0,0,0}; xn[s][ks]=z; }
  __syncthreads();

  // precomputed LDS write bases for the h frag (byte ptrs; +r*16B per row)
  u16* hw0 = &hbuf[1][0] + fragidx(4*q, jj);   // step t even writes hbuf[1]
  u16* hw1 = &hbuf[0][0] + fragidx(4*q, jj);   // step t odd  writes hbuf[0]

  for (int tb = 0; tb < TT/2; ++tb) {
    const int t0 = 2*tb;

    // ---- MLP for steps t0, t0+1 (gx -> fp32 regs) ----------------------
#pragma unroll
    for (int s = 0; s < 2; ++s) {
      floatx4 a = {0.f,0.f,0.f,0.f};
      a = mfma(xc[s][0], w1f[0], a);
      a = mfma(xc[s][1], w1f[1], a);
#pragma unroll
      for (int r = 0; r < 4; ++r) {
        float v = a[r] + b1v; v = v > 0.f ? v : 0.f;
        h1f[s][fragidx(4*q + r, jj)] = f2bf(v);
      }
    }
    barrier_lds();                                 // B1
#pragma unroll
    for (int s = 0; s < 2; ++s) {
      short8 h1a[4];
#pragma unroll
      for (int ks = 0; ks < 4; ++ks) h1a[ks] = *(const short8*)(&h1f[s][0] + ks*512 + lane*8);
      floatx4 a = {0.f,0.f,0.f,0.f};
#pragma unroll
      for (int ks = 0; ks < 4; ++ks) a = mfma(h1a[ks], w2f[ks], a);
#pragma unroll
      for (int r = 0; r < 4; ++r) {
        float v = a[r] + b2v; v = v > 0.f ? v : 0.f;
        h2f[s][fragidx(4*q + r, jj)] = f2bf(v);
      }
    }
    barrier_lds();                                 // B2
    floatx4 agx[2][3];
#pragma unroll
    for (int s = 0; s < 2; ++s) {
      short8 h2a[4];
#pragma unroll
      for (int ks = 0; ks < 4; ++ks) h2a[ks] = *(const short8*)(&h2f[s][0] + ks*512 + lane*8);
#pragma unroll
      for (int g = 0; g < 3; ++g) {
        floatx4 a = {0.f,0.f,0.f,0.f};
#pragma unroll
        for (int ks = 0; ks < 4; ++ks) a = mfma(h2a[ks], wif[g][ks], a);
        agx[s][g] = a;
      }
    }

    // next batch x + done prefetch (consumed after 2 rec steps)
    if (t0 + 2 < TT) {
#pragma unroll
      for (int s = 0; s < 2; ++s) {
        size_t base = ((size_t)(t0+2+s)*BB + b0 + n16)*SS + q*8;
        if constexpr (BF) {
          xn[s][0] = *(const short8*)((const u16*)x + base);
          xn[s][1] = *(const short8*)((const u16*)x + base + 32);
        }
        size_t didx = (size_t)(t0+2+s)*BB + b0 + 4*q;
        if constexpr (BF) draw[s] = *(const u32x2*)((const u16*)done_ + didx);
        else              fdraw[s] = *(const floatx4*)((const float*)done_ + didx);
      }
    }

    // ---- 2 recurrence steps --------------------------------------------
#pragma unroll
    for (int s = 0; s < 2; ++s) {
      const int t = t0 + s, p = t & 1;
      short8 haf[4];
#pragma unroll
      for (int ks = 0; ks < 4; ++ks) haf[ks] = *(const short8*)(&hbuf[p][0] + ks*512 + lane*8);

      // head for t-1: raw logits/value -> workspace (fire-and-forget)
      if (t > 0 && (wv == 1 || wv == 2)) {
        floatx4 a = {0.f,0.f,0.f,0.f};
#pragma unroll
        for (int ks = 0; ks < 4; ++ks) a = mfma(haf[ks], scf[ks], a);
        if (wv == 1) {
#pragma unroll
          for (int r = 0; r < 4; ++r)
            lgws[((size_t)(t-1)*BB + b0 + 4*q + r)*16 + n16] = a[r] + bav;
        } else if (n16 == 0) {
#pragma unroll
          for (int r = 0; r < 4; ++r)
            vws[(size_t)(t-1)*BB + b0 + 4*q + r] = a[r] + bcv;
        }
      }

      floatx4 agh[3];
#pragma unroll
      for (int g = 0; g < 3; ++g) {
        floatx4 a = {0.f,0.f,0.f,0.f};
#pragma unroll
        for (int ks = 0; ks < 4; ++ks) a = mfma(haf[ks], whf[g][ks], a);
        agh[g] = a;
      }

      u16* hw = p ? hw1 : hw0;
#pragma unroll
      for (int r = 0; r < 4; ++r) {
        float s4 = s4cur[s][r];
        float tr = agx[s][0][r] + __builtin_fmaf(s4, agh[0][r], bb0);
        float tz = agx[s][1][r] + __builtin_fmaf(s4, agh[1][r], bb1);
        float xn_ = agx[s][2][r] + bihv2;
        float hn_ = __builtin_fmaf(s4, agh[2][r], bhv2);
        float rg = frcp(1.f + __expf(-tr));
        float zg = frcp(1.f + __expf(-tz));
        float ni = __builtin_fmaf(rg, hn_, xn_);
        float ng = __builtin_fmaf(2.f, frcp(1.f + __expf(-2.f*ni)), -1.f);  // tanh
        float hold = hreg[r] * s4;
        float hnew = __builtin_fmaf(zg, hold - ng, ng);
        hreg[r] = hnew;
        hw[r*8] = f2bf(hnew);
      }
      barrier_lds();                               // step barrier
    }

    // rotate prefetched regs (loads issued ~2 steps ago)
    if (t0 + 2 < TT) {
      if constexpr (BF) {
#pragma unroll
        for (int s = 0; s < 2; ++s) {
          xc[s][0] = xn[s][0]; xc[s][1] = xn[s][1];
          s4cur[s][0] = 1.f - bf2f((u16)(draw[s].x & 0xFFFF));
          s4cur[s][1] = 1.f - bf2f((u16)(draw[s].x >> 16));
          s4cur[s][2] = 1.f - bf2f((u16)(draw[s].y & 0xFFFF));
          s4cur[s][3] = 1.f - bf2f((u16)(draw[s].y >> 16));
        }
      } else {
#pragma unroll
        for (int s = 0; s < 2; ++s) {
          size_t base = ((size_t)(t0+2+s)*BB + b0 + n16)*SS + q*8;
          xc[s][0] = ld8<false>(x, base);
          xc[s][1] = ld8<false>(x, base + 32);
#pragma unroll
          for (int r = 0; r < 4; ++r) s4cur[s][r] = 1.f - fdraw[s][r];
        }
      }
    }
  }

  // epilogue: head for t=511 (h_511 in hbuf[0]) + h_last output from hreg
  {
    if (wv == 1 || wv == 2) {
      short8 haf[4];
#pragma unroll
      for (int ks = 0; ks < 4; ++ks) haf[ks] = *(const short8*)(&hbuf[0][0] + ks*512 + lane*8);
      floatx4 a = {0.f,0.f,0.f,0.f};
#pragma unroll
      for (int ks = 0; ks < 4; ++ks) a = mfma(haf[ks], scf[ks], a);
      if (wv == 1) {
#pragma unroll
        for (int r = 0; r < 4; ++r)
          lgws[((size_t)(TT-1)*BB + b0 + 4*q + r)*16 + n16] = a[r] + bav;
      } else if (n16 == 0) {
#pragma unroll
        for (int r = 0; r < 4; ++r)
          vws[(size_t)(TT-1)*BB + b0 + 4*q + r] = a[r] + bcv;
      }
    }
#pragma unroll
    for (int r = 0; r < 4; ++r)
      st1<BF>(out, (size_t)3*TBR + (size_t)(b0 + 4*q + r)*HH + jj, hreg[r]);
  }
}

// ---------------------------------------------------------------------------
// K3: data-parallel head finisher. One thread per (t,b) row: log_softmax
// over 16 logits, entropy, action gather, value pass-through.
// ---------------------------------------------------------------------------
template<bool BF>
__global__ __launch_bounds__(256) void k_head(
    const float* __restrict__ lgws, const float* __restrict__ vws,
    const int* __restrict__ action, const void* __restrict__ W1,
    void* __restrict__ out)
{
  if (buf_is_bf16((const u16*)W1) != BF) return;
  size_t row = (size_t)blockIdx.x * 256 + threadIdx.x;
  if (row >= (size_t)TBR) return;
  const float* lp = lgws + row*16;
  floatx4 v[4];
#pragma unroll
  for (int i = 0; i < 4; ++i) v[i] = *(const floatx4*)(lp + 4*i);
  float mx = v[0][0];
#pragma unroll
  for (int i = 0; i < 4; ++i)
#pragma unroll
    for (int j = 0; j < 4; ++j) mx = fmaxf(mx, v[i][j]);
  float sum = 0.f, se = 0.f;
#pragma unroll
  for (int i = 0; i < 4; ++i)
#pragma unroll
    for (int j = 0; j < 4; ++j) {
      float d = v[i][j] - mx;
      float e = __expf(d);
      sum += e; se = __builtin_fmaf(e, d, se);
    }
  float ls = __logf(sum);
  int a = action[row];
  float la = lp[a];                       // re-load (L1/L2 hit) -> no reg-indexing
  float lpa = (la - mx) - ls;
  float ent = ls - se * frcp(sum);
  st1<BF>(out, row*3,     lpa);
  st1<BF>(out, row*3 + 1, ent);
  st1<BF>(out, row*3 + 2, vws[row]);
}

// ---------------------------------------------------------------------------
extern "C" void kernel_launch(void* const* d_in, const int* in_sizes, int n_in,
                              void* d_out, int out_size, void* d_ws, size_t ws_size,
                              hipStream_t stream) {
  const void* x    = d_in[0];
  const void* done = d_in[1];
  const int*  act  = (const int*)d_in[2];
  const void* gst  = d_in[3];
  const void* W1   = d_in[4];
  const void* b1   = d_in[5];
  const void* W2   = d_in[6];
  const void* b2   = d_in[7];
  const void* Wih  = d_in[8];
  const void* bih  = d_in[9];
  const void* Whh  = d_in[10];
  const void* bhh  = d_in[11];
  const void* Wa   = d_in[12];
  const void* ba   = d_in[13];
  const void* Wc   = d_in[14];
  const void* bc   = d_in[15];

  float* lgws = (float*)d_ws;                       // [TBR,16] fp32 = 33.6 MB
  float* vws  = lgws + (size_t)16*TBR;              // [TBR]    fp32 =  2.1 MB

  hipLaunchKernelGGL((k_scan<true>),  dim3(64), dim3(512), 0, stream,
                     x, done, gst, W1, b1, W2, b2, Wih, bih,
                     Whh, bhh, Wa, ba, Wc, bc, lgws, vws, d_out);
  hipLaunchKernelGGL((k_scan<false>), dim3(64), dim3(512), 0, stream,
                     x, done, gst, W1, b1, W2, b2, Wih, bih,
                     Whh, bhh, Wa, ba, Wc, bc, lgws, vws, d_out);
  hipLaunchKernelGGL((k_head<true>),  dim3(TBR/256), dim3(256), 0, stream,
                     lgws, vws, act, W1, d_out);
  hipLaunchKernelGGL((k_head<false>), dim3(TBR/256), dim3(256), 0, stream,
                     lgws, vws, act, W1, d_out);
}